// Round 1
// baseline (127.076 us; speedup 1.0000x reference)
//
#include <hip/hip_runtime.h>

// Problem constants (from reference): B=4, S=2048, R=64, C=16, P=5
#define B_DIM 4
#define S_DIM 2048
#define R_DIM 64
#define C_DIM 16
#define NVOX (B_DIM * R_DIM * R_DIM * R_DIM)      // 1,048,576
#define OUT_ELEMS (NVOX * C_DIM)                  // 16,777,216 floats (64 MiB)

// ---------------------------------------------------------------------------
// K1: out[v*16 + c] = b_out[c]   (pure 64 MiB streaming write, float4)
// ---------------------------------------------------------------------------
__global__ __launch_bounds__(256) void init_out_kernel(float* __restrict__ out,
                                                       const float* __restrict__ b_out) {
    float4 bo0 = ((const float4*)b_out)[0];
    float4 bo1 = ((const float4*)b_out)[1];
    float4 bo2 = ((const float4*)b_out)[2];
    float4 bo3 = ((const float4*)b_out)[3];
    float4* o4 = (float4*)out;
    const int n4 = OUT_ELEMS / 4; // 4,194,304
    for (int i = blockIdx.x * blockDim.x + threadIdx.x; i < n4; i += gridDim.x * blockDim.x) {
        int sel = i & 3; // float4 i covers channels (i%4)*4 .. +3
        o4[i] = (sel == 0) ? bo0 : (sel == 1) ? bo1 : (sel == 2) ? bo2 : bo3;
    }
}

// ---------------------------------------------------------------------------
// K2: one wave (64 lanes) per point (B*S = 8192 points).
//  - compute corrections = 0.1*sigmoid(x @ w_poca + b_poca), pos, frac, ivox
//  - counts part: only channel 0 of counts survives -> offsets jj=0..7 with
//    weights 16 (jj<7) / 13 (jj==7); scatter w * w_out[16][c] into out.
//  - gauss part: exp(-d2/STD^2) underflows except (rarely) one offset; for a
//    surviving offset scatter  sum_cf(x[cf]*g grouped by cl) @ w_out  into out.
//    (cl = (jj*16+cf)//125 reproduces the reference's index scramble.)
// ---------------------------------------------------------------------------
__global__ __launch_bounds__(256) void scatter_kernel(const float* __restrict__ positions,
                                                      const float* __restrict__ x,
                                                      const float* __restrict__ w_poca,
                                                      const float* __restrict__ b_poca,
                                                      const float* __restrict__ w_out,
                                                      float* __restrict__ out) {
    const int wid  = (blockIdx.x * blockDim.x + threadIdx.x) >> 6; // point id
    const int lane = threadIdx.x & 63;
    if (wid >= B_DIM * S_DIM) return;
    const int b = wid >> 11; // wid / S_DIM

    const float* xr = x + wid * C_DIM;

    // --- corrections: dot(x[16], w_poca[:,d]) via 64-lane shfl reduce ---
    float p0 = 0.f, p1 = 0.f, p2 = 0.f;
    if (lane < 16) {
        float xv = xr[lane];
        p0 = xv * w_poca[lane * 3 + 0];
        p1 = xv * w_poca[lane * 3 + 1];
        p2 = xv * w_poca[lane * 3 + 2];
    }
    for (int m = 32; m; m >>= 1) {
        p0 += __shfl_xor(p0, m);
        p1 += __shfl_xor(p1, m);
        p2 += __shfl_xor(p2, m);
    }

    const float c0 = 0.1f / (1.f + expf(-(p0 + b_poca[0])));
    const float c1 = 0.1f / (1.f + expf(-(p1 + b_poca[1])));
    const float c2 = 0.1f / (1.f + expf(-(p2 + b_poca[2])));

    const float posx = (positions[wid * 3 + 0] + c0) * (float)R_DIM;
    const float posy = (positions[wid * 3 + 1] + c1) * (float)R_DIM;
    const float posz = (positions[wid * 3 + 2] + c2) * (float)R_DIM;

    const float frx = posx - rintf(posx);
    const float fry = posy - rintf(posy);
    const float frz = posz - rintf(posz);

    const int ivx = (int)posx; // pos > 0, trunc == floor == astype(int32)
    const int ivy = (int)posy;
    const int ivz = (int)posz;

    // --- counts channel-0 scatter: 8 offsets x 16 channels = 128 tasks ---
    // off[jj] = (jj//25 - 2, (jj//5)%5 - 2, jj%5 - 2); jj<8 => ox = -2.
    {
        const int vx = min(max(ivx - 2, 0), R_DIM - 1);
        for (int t = lane; t < 128; t += 64) {
            const int jj = t >> 4;
            const int c  = t & 15;
            const int oy = (jj >= 5) ? -1 : -2;
            const int oz = (jj - ((jj >= 5) ? 5 : 0)) - 2; // jj%5 - 2
            const int vy = min(max(ivy + oy, 0), R_DIM - 1);
            const int vz = min(max(ivz + oz, 0), R_DIM - 1);
            const int voxlin = (b << 18) + (vx << 12) + (vy << 6) + vz;
            const float w = (jj == 7) ? 13.f : 16.f;
            atomicAdd(out + voxlin * C_DIM + c, w * w_out[16 * C_DIM + c]);
        }
    }

    // --- gaussian scatter: survives only when exp doesn't underflow ---
    const float STD2 = (float)((0.6 / 64.0) * (0.6 / 64.0));
    for (int jj = lane; jj < 125; jj += 64) {
        const int ox = (jj / 25) - 2;
        const int oy = ((jj / 5) % 5) - 2;
        const int oz = (jj % 5) - 2;
        const float dx = frx + (float)ox;
        const float dy = fry + (float)oy;
        const float dz = frz + (float)oz;
        const float d2 = dx * dx + dy * dy + dz * dz;
        const float arg = -d2 / STD2;
        if (arg > -100.f) { // exp(-100) ~ 3.7e-44: below any tolerance
            const float g = expf(arg);
            const int vx = min(max(ivx + ox, 0), R_DIM - 1);
            const int vy = min(max(ivy + oy, 0), R_DIM - 1);
            const int vz = min(max(ivz + oz, 0), R_DIM - 1);
            const int base = ((b << 18) + (vx << 12) + (vy << 6) + vz) * C_DIM;
            // channel scramble: value x[cf]*g goes to channel cl=(jj*16+cf)//125
            const int I0 = jj * 16;
            const int k0 = I0 / 125;
            const int k1 = (I0 + 15) / 125;
            float s0 = 0.f, s1 = 0.f;
            for (int cf = 0; cf < 16; ++cf) {
                const float val = xr[cf] * g;
                if ((I0 + cf) / 125 == k0) s0 += val; else s1 += val;
            }
            for (int c = 0; c < 16; ++c) {
                float delta = s0 * w_out[k0 * C_DIM + c];
                if (k1 != k0) delta += s1 * w_out[k1 * C_DIM + c];
                atomicAdd(out + base + c, delta);
            }
        }
    }
}

extern "C" void kernel_launch(void* const* d_in, const int* in_sizes, int n_in,
                              void* d_out, int out_size, void* d_ws, size_t ws_size,
                              hipStream_t stream) {
    const float* positions = (const float*)d_in[0]; // (B,S,3)
    const float* x         = (const float*)d_in[1]; // (B,S,C)
    const float* w_poca    = (const float*)d_in[2]; // (C,3)
    const float* b_poca    = (const float*)d_in[3]; // (3,)
    const float* w_out     = (const float*)d_in[4]; // (C+1,C)
    const float* b_out     = (const float*)d_in[5]; // (C,)
    float* out = (float*)d_out;

    // K1: initialize out = b_out (harness re-poisons d_out before every call)
    init_out_kernel<<<2048, 256, 0, stream>>>(out, b_out);

    // K2: one wave per point; 8192 waves -> 2048 blocks of 256 (4 waves each)
    const int npts = B_DIM * S_DIM;
    scatter_kernel<<<(npts * 64) / 256, 256, 0, stream>>>(positions, x, w_poca,
                                                          b_poca, w_out, out);
}

// Round 3
// 96.053 us; speedup vs baseline: 1.3230x; 1.3230x over previous
//
#include <hip/hip_runtime.h>

// Problem constants (from reference): B=4, S=2048, R=64, C=16, P=5
#define B_DIM 4
#define S_DIM 2048
#define R_DIM 64
#define C_DIM 16
#define NPTS  (B_DIM * S_DIM)                    // 8192
#define NVOX  (B_DIM * R_DIM * R_DIM * R_DIM)    // 1,048,576
#define OUT_ELEMS (NVOX * C_DIM)                 // 16,777,216 floats (64 MiB)

// ws layout (in floats):
//   [0, NVOX)        : per-voxel counts0 accumulator (scalar)
//   [NVOX]           : gauss-survivor entry counter (uint)
//   [NVOX+1, ...)    : entries, 3 words each: {uint voxlin, float s0, float s1}
#define CTR_OFF NVOX
#define ENT_OFF (NVOX + 1)
#define MAX_ENT 8192

// ---------------------------------------------------------------------------
// K0: zero the counts grid + entry counter (ws is poisoned 0xAA every call)
// ---------------------------------------------------------------------------
__global__ __launch_bounds__(256) void zero_ws_kernel(float* __restrict__ ws) {
    const int i = blockIdx.x * blockDim.x + threadIdx.x; // < NVOX/4
    ((float4*)ws)[i] = make_float4(0.f, 0.f, 0.f, 0.f);
    if (i == 0) ((unsigned*)ws)[CTR_OFF] = 0u;
}

// ---------------------------------------------------------------------------
// K1: one THREAD per point.
//  - corrections = 0.1*sigmoid(x @ w_poca + b_poca); pos; frac; ivox
//  - counts0: only I in [0,125) survive the channel-0 slice -> offsets jj=0..7
//    (all with ox=-2) carrying weight 16 (jj<7) / 13 (jj==7). Scatter the
//    SCALAR weight into ws counts grid (8 atomics per point).
//  - gauss: exp(-d2/STD^2) with STD=0.6/64 underflows for every offset except
//    possibly off=(0,0,0) (any other offset has d2>=0.25 -> arg<=-2800).
//    For jj=62 the reference's channel scramble maps value channels 0..7 ->
//    grid ch 7 and 8..15 -> grid ch 8, so a survivor is fully described by
//    (voxlin, s0=g*sum(x[0:8]), s1=g*sum(x[8:16])) -> append to list.
// ---------------------------------------------------------------------------
__global__ __launch_bounds__(256) void point_kernel(const float* __restrict__ positions,
                                                    const float* __restrict__ x,
                                                    const float* __restrict__ w_poca,
                                                    const float* __restrict__ b_poca,
                                                    float* __restrict__ ws) {
    const int p = blockIdx.x * blockDim.x + threadIdx.x;
    if (p >= NPTS) return;
    const int b = p >> 11; // p / S_DIM

    const float* xr = x + p * C_DIM;
    float xv[C_DIM];
    {
        float4 x0 = ((const float4*)xr)[0];
        float4 x1 = ((const float4*)xr)[1];
        float4 x2 = ((const float4*)xr)[2];
        float4 x3 = ((const float4*)xr)[3];
        xv[0]=x0.x; xv[1]=x0.y; xv[2]=x0.z; xv[3]=x0.w;
        xv[4]=x1.x; xv[5]=x1.y; xv[6]=x1.z; xv[7]=x1.w;
        xv[8]=x2.x; xv[9]=x2.y; xv[10]=x2.z; xv[11]=x2.w;
        xv[12]=x3.x; xv[13]=x3.y; xv[14]=x3.z; xv[15]=x3.w;
    }

    // corrections = 0.1 * sigmoid(x @ w_poca + b_poca)
    float a0 = b_poca[0], a1 = b_poca[1], a2 = b_poca[2];
    #pragma unroll
    for (int cf = 0; cf < C_DIM; ++cf) {
        a0 = fmaf(xv[cf], w_poca[cf * 3 + 0], a0);
        a1 = fmaf(xv[cf], w_poca[cf * 3 + 1], a1);
        a2 = fmaf(xv[cf], w_poca[cf * 3 + 2], a2);
    }
    const float c0 = 0.1f / (1.f + expf(-a0));
    const float c1 = 0.1f / (1.f + expf(-a1));
    const float c2 = 0.1f / (1.f + expf(-a2));

    const float posx = (positions[p * 3 + 0] + c0) * (float)R_DIM;
    const float posy = (positions[p * 3 + 1] + c1) * (float)R_DIM;
    const float posz = (positions[p * 3 + 2] + c2) * (float)R_DIM;

    const float frx = posx - rintf(posx);
    const float fry = posy - rintf(posy);
    const float frz = posz - rintf(posz);

    const int ivx = (int)posx; // pos > 0 so trunc == astype(int32)
    const int ivy = (int)posy;
    const int ivz = (int)posz;

    // --- counts0 scatter: jj=0..7, ox=-2, weight 16 (jj<7) / 13 (jj==7) ---
    {
        const int vx = min(max(ivx - 2, 0), R_DIM - 1);
        const int base = (b << 18) | (vx << 12);
        #pragma unroll
        for (int jj = 0; jj < 8; ++jj) {
            const int oy = (jj >= 5) ? -1 : -2;
            const int oz = (jj - ((jj >= 5) ? 5 : 0)) - 2; // jj%5 - 2
            const int vy = min(max(ivy + oy, 0), R_DIM - 1);
            const int vz = min(max(ivz + oz, 0), R_DIM - 1);
            atomicAdd(ws + (base | (vy << 6) | vz), (jj == 7) ? 13.f : 16.f);
        }
    }

    // --- gauss survivor check: only off=(0,0,0) can be non-underflow ---
    const float INV_STD2 = 1.0f / (float)((0.6 / 64.0) * (0.6 / 64.0));
    const float d2 = frx * frx + fry * fry + frz * frz;
    const float arg = -d2 * INV_STD2;
    if (arg > -100.f) { // exp(-100) ~ 3.7e-44, below any tolerance
        const float g = expf(arg);
        float s0 = 0.f, s1 = 0.f;
        #pragma unroll
        for (int cf = 0; cf < 8; ++cf)  s0 += xv[cf];
        #pragma unroll
        for (int cf = 8; cf < 16; ++cf) s1 += xv[cf];
        const int vx = min(max(ivx, 0), R_DIM - 1);
        const int vy = min(max(ivy, 0), R_DIM - 1);
        const int vz = min(max(ivz, 0), R_DIM - 1);
        const unsigned voxlin = (b << 18) | (vx << 12) | (vy << 6) | vz;
        const unsigned e = atomicAdd((unsigned*)ws + CTR_OFF, 1u);
        if (e < MAX_ENT) {
            float* ent = ws + ENT_OFF + 3u * e;
            ((unsigned*)ent)[0] = voxlin;
            ent[1] = g * s0;
            ent[2] = g * s1;
        }
    }
}

// ---------------------------------------------------------------------------
// K2: streaming compose, out[v,c] = b_out[c] + cnt[v] * w_out[16,c]
//     one float4 store per thread (coalesced), 64 MiB write + 4 MiB read.
// ---------------------------------------------------------------------------
__global__ __launch_bounds__(256) void compose_kernel(const float* __restrict__ ws,
                                                      const float* __restrict__ w_out,
                                                      const float* __restrict__ b_out,
                                                      float* __restrict__ out) {
    const int i = blockIdx.x * blockDim.x + threadIdx.x; // float4 index
    const int v = i >> 2;
    const int sel = i & 3;
    const float cnt = ws[v];
    const float4 bo = ((const float4*)b_out)[sel];
    const float4 w16 = ((const float4*)(w_out + 16 * C_DIM))[sel];
    float4 r;
    r.x = fmaf(cnt, w16.x, bo.x);
    r.y = fmaf(cnt, w16.y, bo.y);
    r.z = fmaf(cnt, w16.z, bo.z);
    r.w = fmaf(cnt, w16.w, bo.w);
    ((float4*)out)[i] = r;
}

// ---------------------------------------------------------------------------
// K3: apply the (rare) gauss survivors: out[voxlin,c] += s0*w_out[7,c] + s1*w_out[8,c]
// ---------------------------------------------------------------------------
__global__ __launch_bounds__(256) void fixup_kernel(const float* __restrict__ ws,
                                                    const float* __restrict__ w_out,
                                                    float* __restrict__ out) {
    const unsigned n = min(((const unsigned*)ws)[CTR_OFF], (unsigned)MAX_ENT);
    const int c = threadIdx.x & 15;
    const float w7 = w_out[7 * C_DIM + c];
    const float w8 = w_out[8 * C_DIM + c];
    for (unsigned e = threadIdx.x >> 4; e < n; e += blockDim.x >> 4) {
        const float* ent = ws + ENT_OFF + 3u * e;
        const unsigned voxlin = ((const unsigned*)ent)[0];
        const float s0 = ent[1];
        const float s1 = ent[2];
        atomicAdd(out + voxlin * C_DIM + c, fmaf(s0, w7, s1 * w8));
    }
}

extern "C" void kernel_launch(void* const* d_in, const int* in_sizes, int n_in,
                              void* d_out, int out_size, void* d_ws, size_t ws_size,
                              hipStream_t stream) {
    const float* positions = (const float*)d_in[0]; // (B,S,3)
    const float* x         = (const float*)d_in[1]; // (B,S,C)
    const float* w_poca    = (const float*)d_in[2]; // (C,3)
    const float* b_poca    = (const float*)d_in[3]; // (3,)
    const float* w_out     = (const float*)d_in[4]; // (C+1,C)
    const float* b_out     = (const float*)d_in[5]; // (C,)
    float* out = (float*)d_out;
    float* ws  = (float*)d_ws;

    // K0: zero counts grid + entry counter (NVOX/4 float4 stores)
    zero_ws_kernel<<<NVOX / 4 / 256, 256, 0, stream>>>(ws);

    // K1: one thread per point (8192 threads)
    point_kernel<<<NPTS / 256, 256, 0, stream>>>(positions, x, w_poca, b_poca, ws);

    // K2: streaming compose (4M float4 stores)
    compose_kernel<<<OUT_ELEMS / 4 / 256, 256, 0, stream>>>(ws, w_out, b_out, out);

    // K3: rare gauss survivors
    fixup_kernel<<<1, 256, 0, stream>>>(ws, w_out, out);
}